// Round 7
// baseline (106.212 us; speedup 1.0000x reference)
//
#include <hip/hip_runtime.h>

#define BS 8192
#define D  128
#define TI 256              // i-rows per block (4 waves x 64)
#define JCHUNK 256          // j's per block chunk
#define NJC (BS / JCHUNK)   // 32 (grid.y)
#define NHP 4               // half-panels per chunk (64 j-rows each)

typedef __bf16 bf16x8 __attribute__((ext_vector_type(8)));
typedef float  f32x16 __attribute__((ext_vector_type(16)));

// ---------------------------------------------------------------------------
// pack: feats -> fragment-major bf16 for BOTH anchor (Apack) and positive
// (Ppack), plus the fp32 row reductions (a_sq, p_sq, pd2). Layout (verified
// correct in R6): piece ((tile*8 + s)*64 + lane) holds the 8 bf16 operand
// elements for MFMA lane `lane` at k-step s of 32-row tile `tile`:
//   row = tile*32 + (lane&31), k = s*16 + (lane>>5)*8 .. +8
// Thread (r=tid>>3, kb=tid&7) reads 16 contiguous fp32 of row tile*32+r
// (fully coalesced) and emits the lo/hi pieces of step s=kb.
// ---------------------------------------------------------------------------
__global__ __launch_bounds__(256) void pack_kernel(
        const float* __restrict__ feats,
        __bf16* __restrict__ Apack, __bf16* __restrict__ Ppack,
        float* __restrict__ a_sq, float* __restrict__ p_sq,
        float* __restrict__ pd2)
{
    const int tile = blockIdx.x;          // 0..255
    const int tid  = threadIdx.x;
    const int r    = tid >> 3;            // row within tile, 0..31
    const int kb   = tid & 7;             // k-block = MFMA step s, 0..7
    const int row  = tile * 32 + r;

    const float4* asrc = (const float4*)(feats + (size_t)row * D + kb * 16);
    const float4* psrc = (const float4*)(feats + (size_t)(row + BS) * D + kb * 16);
    float4 a0 = asrc[0], a1 = asrc[1], a2 = asrc[2], a3 = asrc[3];
    float4 p0 = psrc[0], p1 = psrc[1], p2 = psrc[2], p3 = psrc[3];

    bf16x8 alo, ahi, plo, phi;
    alo[0]=(__bf16)a0.x; alo[1]=(__bf16)a0.y; alo[2]=(__bf16)a0.z; alo[3]=(__bf16)a0.w;
    alo[4]=(__bf16)a1.x; alo[5]=(__bf16)a1.y; alo[6]=(__bf16)a1.z; alo[7]=(__bf16)a1.w;
    ahi[0]=(__bf16)a2.x; ahi[1]=(__bf16)a2.y; ahi[2]=(__bf16)a2.z; ahi[3]=(__bf16)a2.w;
    ahi[4]=(__bf16)a3.x; ahi[5]=(__bf16)a3.y; ahi[6]=(__bf16)a3.z; ahi[7]=(__bf16)a3.w;
    plo[0]=(__bf16)p0.x; plo[1]=(__bf16)p0.y; plo[2]=(__bf16)p0.z; plo[3]=(__bf16)p0.w;
    plo[4]=(__bf16)p1.x; plo[5]=(__bf16)p1.y; plo[6]=(__bf16)p1.z; plo[7]=(__bf16)p1.w;
    phi[0]=(__bf16)p2.x; phi[1]=(__bf16)p2.y; phi[2]=(__bf16)p2.z; phi[3]=(__bf16)p2.w;
    phi[4]=(__bf16)p3.x; phi[5]=(__bf16)p3.y; phi[6]=(__bf16)p3.z; phi[7]=(__bf16)p3.w;

    const size_t pb = ((size_t)tile * 8 + kb) * 64;
    ((bf16x8*)Apack)[pb + r]      = alo;
    ((bf16x8*)Apack)[pb + 32 + r] = ahi;
    ((bf16x8*)Ppack)[pb + r]      = plo;
    ((bf16x8*)Ppack)[pb + 32 + r] = phi;

    float sa = a0.x*a0.x + a0.y*a0.y + a0.z*a0.z + a0.w*a0.w
             + a1.x*a1.x + a1.y*a1.y + a1.z*a1.z + a1.w*a1.w
             + a2.x*a2.x + a2.y*a2.y + a2.z*a2.z + a2.w*a2.w
             + a3.x*a3.x + a3.y*a3.y + a3.z*a3.z + a3.w*a3.w;
    float sp = p0.x*p0.x + p0.y*p0.y + p0.z*p0.z + p0.w*p0.w
             + p1.x*p1.x + p1.y*p1.y + p1.z*p1.z + p1.w*p1.w
             + p2.x*p2.x + p2.y*p2.y + p2.z*p2.z + p2.w*p2.w
             + p3.x*p3.x + p3.y*p3.y + p3.z*p3.z + p3.w*p3.w;
    float d;
    float sd = 0.0f;
    d = a0.x-p0.x; sd += d*d;  d = a0.y-p0.y; sd += d*d;
    d = a0.z-p0.z; sd += d*d;  d = a0.w-p0.w; sd += d*d;
    d = a1.x-p1.x; sd += d*d;  d = a1.y-p1.y; sd += d*d;
    d = a1.z-p1.z; sd += d*d;  d = a1.w-p1.w; sd += d*d;
    d = a2.x-p2.x; sd += d*d;  d = a2.y-p2.y; sd += d*d;
    d = a2.z-p2.z; sd += d*d;  d = a2.w-p2.w; sd += d*d;
    d = a3.x-p3.x; sd += d*d;  d = a3.y-p3.y; sd += d*d;
    d = a3.z-p3.z; sd += d*d;  d = a3.w-p3.w; sd += d*d;

    // reduce across the 8 kb-lanes sharing this row (contiguous lane group)
    #pragma unroll
    for (int off = 1; off <= 4; off <<= 1) {
        sa += __shfl_xor(sa, off, 64);
        sp += __shfl_xor(sp, off, 64);
        sd += __shfl_xor(sd, off, 64);
    }
    if (kb == 0) { a_sq[row] = sa; p_sq[row] = sp; pd2[row] = sd; }
}

// ---------------------------------------------------------------------------
// max kernel: block = 256 i-rows x 256 j-chunk; 4 waves x 64 rows. A frags
// (2 sets) in registers for the whole kernel, loaded COALESCED from Apack.
// B streams as 4 half-panels (64 j-rows = 1024 pieces = 16 KB) through
// double-buffered LDS; staging is a linear fragment-order copy (coalesced
// global read, linear LDS write, conflict-free lane-contiguous ds_read_b128).
//
// acc initialized to -p_sq[col]/2, so after K-loop acc = cross - p_sq/2 and
// min_j d2 = a_sq - 2 * max_j acc  -> epilogue = one v_max per reg.
//
// mfma_f32_32x32x16_bf16 C/D layout (HW-verified, learn_hip m74/m101):
//   col = lane&31, row = (reg&3) + 8*(reg>>2) + 4*(lane>>5)
// ---------------------------------------------------------------------------
__global__ __launch_bounds__(256, 3) void max_kernel(
        const __bf16* __restrict__ Apack, const __bf16* __restrict__ Ppack,
        const float* __restrict__ p_sq, float* __restrict__ partmax)
{
    __shared__ __bf16 smem[2 * 8192];           // 2 x 16 KB half-panel bufs

    const int tid  = threadIdx.x;
    const int wave = tid >> 6;
    const int lane = tid & 63;
    const int l31  = lane & 31;
    const int half = lane >> 5;

    const int i0    = blockIdx.x * TI + wave * 64;    // wave's 64 anchor rows
    const int itile = i0 >> 5;
    const int jbase = blockIdx.y * JCHUNK;

    // A fragments, coalesced 1 KB wave-loads from fragment-major Apack
    bf16x8 afA[8], afB[8];
    {
        const bf16x8* ap = (const bf16x8*)Apack;
        #pragma unroll
        for (int s = 0; s < 8; ++s) {
            afA[s] = ap[((size_t)itile * 8 + s) * 64 + lane];
            afB[s] = ap[((size_t)(itile + 1) * 8 + s) * 64 + lane];
        }
    }

    float rmaxA[16], rmaxB[16];
    #pragma unroll
    for (int r = 0; r < 16; ++r) { rmaxA[r] = -3.0e38f; rmaxB[r] = -3.0e38f; }

    // piece stream for this block's j-chunk (1024 pieces per half-panel)
    const bf16x8* gp = (const bf16x8*)Ppack + ((size_t)(jbase >> 5) * 8) * 64;
    bf16x8* sm = (bf16x8*)smem;

    bf16x8 tmp[4];
    #pragma unroll
    for (int h = 0; h < 4; ++h) tmp[h] = gp[tid + h * 256];
    #pragma unroll
    for (int h = 0; h < 4; ++h) sm[tid + h * 256] = tmp[h];
    __syncthreads();

    #pragma unroll
    for (int hp = 0; hp < NHP; ++hp) {
        if (hp + 1 < NHP) {
            #pragma unroll
            for (int h = 0; h < 4; ++h)
                tmp[h] = gp[(hp + 1) * 1024 + tid + h * 256];
        }

        const bf16x8* buf = sm + (hp & 1) * 1024;
        #pragma unroll
        for (int t = 0; t < 2; ++t) {
            const float ci = -0.5f * p_sq[jbase + (hp * 2 + t) * 32 + l31];
            f32x16 acc0, acc1;
            #pragma unroll
            for (int r = 0; r < 16; ++r) { acc0[r] = ci; acc1[r] = ci; }
            #pragma unroll
            for (int s = 0; s < 8; ++s) {
                bf16x8 b = buf[(t * 8 + s) * 64 + lane];
                acc0 = __builtin_amdgcn_mfma_f32_32x32x16_bf16(afA[s], b, acc0,
                                                               0, 0, 0);
                acc1 = __builtin_amdgcn_mfma_f32_32x32x16_bf16(afB[s], b, acc1,
                                                               0, 0, 0);
            }
            #pragma unroll
            for (int r = 0; r < 16; ++r) {
                rmaxA[r] = fmaxf(rmaxA[r], acc0[r]);
                rmaxB[r] = fmaxf(rmaxB[r], acc1[r]);
            }
        }

        if (hp + 1 < NHP) {
            bf16x8* w = sm + ((hp + 1) & 1) * 1024;
            #pragma unroll
            for (int h = 0; h < 4; ++h) w[tid + h * 256] = tmp[h];
            __syncthreads();
        }
    }

    // max across the 32 columns (lanes sharing the same half)
    #pragma unroll
    for (int r = 0; r < 16; ++r) {
        float vA = rmaxA[r], vB = rmaxB[r];
        #pragma unroll
        for (int off = 1; off <= 16; off <<= 1) {
            vA = fmaxf(vA, __shfl_xor(vA, off, 64));
            vB = fmaxf(vB, __shfl_xor(vB, off, 64));
        }
        rmaxA[r] = vA; rmaxB[r] = vB;
    }
    if (l31 == 0) {
        float* dst = partmax + (size_t)blockIdx.y * BS + i0;
        #pragma unroll
        for (int r = 0; r < 16; ++r) {
            int row = (r & 3) + 8 * (r >> 2) + 4 * half;
            dst[row]      = rmaxA[r];
            dst[row + 32] = rmaxB[r];
        }
    }
}

// ---------------------------------------------------------------------------
// fin stage 1: 32 blocks x 256 threads; thread handles exactly one i.
// min_j d2 = a_sq[i] - 2 * max_c partmax[c][i]
// ---------------------------------------------------------------------------
__global__ __launch_bounds__(256) void fin1_kernel(
        const float* __restrict__ partmax, const float* __restrict__ a_sq,
        const float* __restrict__ pd2, float* __restrict__ bsum)
{
    __shared__ float ssum[4];
    const int t = threadIdx.x;
    const int i = blockIdx.x * 256 + t;

    float m = -3.0e38f;
    #pragma unroll
    for (int c = 0; c < NJC; ++c)
        m = fmaxf(m, partmax[c * BS + i]);
    float negd = sqrtf(fmaxf(fmaf(-2.0f, m, a_sq[i]), 0.0f));
    float posd = sqrtf(pd2[i]);
    float sum = fmaxf(posd - negd + 1.0f, 0.0f);

    #pragma unroll
    for (int off = 32; off >= 1; off >>= 1) sum += __shfl_xor(sum, off, 64);
    if ((t & 63) == 0) ssum[t >> 6] = sum;
    __syncthreads();
    if (t == 0)
        bsum[blockIdx.x] = ssum[0] + ssum[1] + ssum[2] + ssum[3];
}

// fin stage 2: one wave sums the 32 block partials.
__global__ __launch_bounds__(64) void fin2_kernel(
        const float* __restrict__ bsum, float* __restrict__ out)
{
    const int t = threadIdx.x;
    float v = (t < 32) ? bsum[t] : 0.0f;
    #pragma unroll
    for (int off = 32; off >= 1; off >>= 1) v += __shfl_xor(v, off, 64);
    if (t == 0) out[0] = v / (float)BS;
}

// ---------------------------------------------------------------------------
extern "C" void kernel_launch(void* const* d_in, const int* in_sizes, int n_in,
                              void* d_out, int out_size, void* d_ws,
                              size_t ws_size, hipStream_t stream)
{
    const float* feats = (const float*)d_in[0];

    char* ws = (char*)d_ws;
    __bf16* Apack = (__bf16*)ws;  ws += (size_t)BS * D * 2;   // 2 MB
    __bf16* Ppack = (__bf16*)ws;  ws += (size_t)BS * D * 2;   // 2 MB
    float* a_sq   = (float*)ws;   ws += (size_t)BS * 4;
    float* p_sq   = (float*)ws;   ws += (size_t)BS * 4;
    float* pd2    = (float*)ws;   ws += (size_t)BS * 4;
    float* partmax = (float*)ws;  ws += (size_t)NJC * BS * 4; // 1 MB
    float* bsum   = (float*)ws;   ws += 32 * 4;

    pack_kernel<<<BS / 32, 256, 0, stream>>>(feats, Apack, Ppack,
                                             a_sq, p_sq, pd2);
    dim3 grid(BS / TI, NJC);
    max_kernel<<<grid, 256, 0, stream>>>(Apack, Ppack, p_sq, partmax);
    fin1_kernel<<<BS / 256, 256, 0, stream>>>(partmax, a_sq, pd2, bsum);
    fin2_kernel<<<1, 64, 0, stream>>>(bsum, (float*)d_out);
}

// Round 8
// 82.977 us; speedup vs baseline: 1.2800x; 1.2800x over previous
//
#include <hip/hip_runtime.h>

#define BS 8192
#define D  128
#define TI 256              // i-rows per block (4 waves x 64)
#define JCHUNK 512          // j's per block chunk
#define NJC (BS / JCHUNK)   // 16 (grid.y)
#define NHP 8               // half-panels per chunk (64 j-rows each)

typedef __bf16 bf16x8 __attribute__((ext_vector_type(8)));
typedef float  f32x16 __attribute__((ext_vector_type(16)));

// ---------------------------------------------------------------------------
// pack: feats -> fragment-major bf16 for BOTH anchor (Apack) and positive
// (Ppack), plus the fp32 row reductions (a_sq, p_sq, pd2). Layout (verified
// correct in R6/R7): piece ((tile*8 + s)*64 + lane) holds the 8 bf16 operand
// elements for MFMA lane `lane` at k-step s of 32-row tile `tile`:
//   row = tile*32 + (lane&31), k = s*16 + (lane>>5)*8 .. +8
// Thread (r=tid>>3, kb=tid&7) reads 16 contiguous fp32 of row tile*32+r
// (fully coalesced) and emits the lo/hi pieces of step s=kb.
// ---------------------------------------------------------------------------
__global__ __launch_bounds__(256) void pack_kernel(
        const float* __restrict__ feats,
        __bf16* __restrict__ Apack, __bf16* __restrict__ Ppack,
        float* __restrict__ a_sq, float* __restrict__ p_sq,
        float* __restrict__ pd2)
{
    const int tile = blockIdx.x;          // 0..255
    const int tid  = threadIdx.x;
    const int r    = tid >> 3;            // row within tile, 0..31
    const int kb   = tid & 7;             // k-block = MFMA step s, 0..7
    const int row  = tile * 32 + r;

    const float4* asrc = (const float4*)(feats + (size_t)row * D + kb * 16);
    const float4* psrc = (const float4*)(feats + (size_t)(row + BS) * D + kb * 16);
    float4 a0 = asrc[0], a1 = asrc[1], a2 = asrc[2], a3 = asrc[3];
    float4 p0 = psrc[0], p1 = psrc[1], p2 = psrc[2], p3 = psrc[3];

    bf16x8 alo, ahi, plo, phi;
    alo[0]=(__bf16)a0.x; alo[1]=(__bf16)a0.y; alo[2]=(__bf16)a0.z; alo[3]=(__bf16)a0.w;
    alo[4]=(__bf16)a1.x; alo[5]=(__bf16)a1.y; alo[6]=(__bf16)a1.z; alo[7]=(__bf16)a1.w;
    ahi[0]=(__bf16)a2.x; ahi[1]=(__bf16)a2.y; ahi[2]=(__bf16)a2.z; ahi[3]=(__bf16)a2.w;
    ahi[4]=(__bf16)a3.x; ahi[5]=(__bf16)a3.y; ahi[6]=(__bf16)a3.z; ahi[7]=(__bf16)a3.w;
    plo[0]=(__bf16)p0.x; plo[1]=(__bf16)p0.y; plo[2]=(__bf16)p0.z; plo[3]=(__bf16)p0.w;
    plo[4]=(__bf16)p1.x; plo[5]=(__bf16)p1.y; plo[6]=(__bf16)p1.z; plo[7]=(__bf16)p1.w;
    phi[0]=(__bf16)p2.x; phi[1]=(__bf16)p2.y; phi[2]=(__bf16)p2.z; phi[3]=(__bf16)p2.w;
    phi[4]=(__bf16)p3.x; phi[5]=(__bf16)p3.y; phi[6]=(__bf16)p3.z; phi[7]=(__bf16)p3.w;

    const size_t pb = ((size_t)tile * 8 + kb) * 64;
    ((bf16x8*)Apack)[pb + r]      = alo;
    ((bf16x8*)Apack)[pb + 32 + r] = ahi;
    ((bf16x8*)Ppack)[pb + r]      = plo;
    ((bf16x8*)Ppack)[pb + 32 + r] = phi;

    float sa = a0.x*a0.x + a0.y*a0.y + a0.z*a0.z + a0.w*a0.w
             + a1.x*a1.x + a1.y*a1.y + a1.z*a1.z + a1.w*a1.w
             + a2.x*a2.x + a2.y*a2.y + a2.z*a2.z + a2.w*a2.w
             + a3.x*a3.x + a3.y*a3.y + a3.z*a3.z + a3.w*a3.w;
    float sp = p0.x*p0.x + p0.y*p0.y + p0.z*p0.z + p0.w*p0.w
             + p1.x*p1.x + p1.y*p1.y + p1.z*p1.z + p1.w*p1.w
             + p2.x*p2.x + p2.y*p2.y + p2.z*p2.z + p2.w*p2.w
             + p3.x*p3.x + p3.y*p3.y + p3.z*p3.z + p3.w*p3.w;
    float d;
    float sd = 0.0f;
    d = a0.x-p0.x; sd += d*d;  d = a0.y-p0.y; sd += d*d;
    d = a0.z-p0.z; sd += d*d;  d = a0.w-p0.w; sd += d*d;
    d = a1.x-p1.x; sd += d*d;  d = a1.y-p1.y; sd += d*d;
    d = a1.z-p1.z; sd += d*d;  d = a1.w-p1.w; sd += d*d;
    d = a2.x-p2.x; sd += d*d;  d = a2.y-p2.y; sd += d*d;
    d = a2.z-p2.z; sd += d*d;  d = a2.w-p2.w; sd += d*d;
    d = a3.x-p3.x; sd += d*d;  d = a3.y-p3.y; sd += d*d;
    d = a3.z-p3.z; sd += d*d;  d = a3.w-p3.w; sd += d*d;

    // reduce across the 8 kb-lanes sharing this row (contiguous lane group)
    #pragma unroll
    for (int off = 1; off <= 4; off <<= 1) {
        sa += __shfl_xor(sa, off, 64);
        sp += __shfl_xor(sp, off, 64);
        sd += __shfl_xor(sd, off, 64);
    }
    if (kb == 0) { a_sq[row] = sa; p_sq[row] = sp; pd2[row] = sd; }
}

// ---------------------------------------------------------------------------
// max kernel: block = 256 i-rows x 512 j-chunk; 4 waves x 64 rows. A frags
// (2 sets) in registers for the whole kernel, loaded COALESCED from Apack.
// B streams as 8 half-panels (64 j-rows = 1024 pieces = 16 KB) through
// double-buffered LDS; staging is a linear fragment-order copy (coalesced
// global read, linear LDS write, conflict-free lane-contiguous ds_read_b128).
//
// NOTE: __launch_bounds__(256, 2) — NOT 3. The (256,3) variant caps the
// unified VGPR+AGPR budget at ~170 and the compiler spills ~60 dwords/thread
// (R7: 60 MB WRITE_SIZE, 52 us). At 2 waves/SIMD the ~190-reg footprint
// fits with zero spill (R5 proof).
//
// acc initialized to -p_sq[col]/2, so after K-loop acc = cross - p_sq/2 and
// min_j d2 = a_sq - 2 * max_j acc  -> epilogue = one v_max per reg.
//
// mfma_f32_32x32x16_bf16 C/D layout (HW-verified, learn_hip m74/m101):
//   col = lane&31, row = (reg&3) + 8*(reg>>2) + 4*(lane>>5)
// ---------------------------------------------------------------------------
__global__ __launch_bounds__(256, 2) void max_kernel(
        const __bf16* __restrict__ Apack, const __bf16* __restrict__ Ppack,
        const float* __restrict__ p_sq, float* __restrict__ partmax)
{
    __shared__ __bf16 smem[2 * 8192];           // 2 x 16 KB half-panel bufs

    const int tid  = threadIdx.x;
    const int wave = tid >> 6;
    const int lane = tid & 63;
    const int l31  = lane & 31;
    const int half = lane >> 5;

    const int i0    = blockIdx.x * TI + wave * 64;    // wave's 64 anchor rows
    const int itile = i0 >> 5;
    const int jbase = blockIdx.y * JCHUNK;

    // A fragments, coalesced 1 KB wave-loads from fragment-major Apack
    bf16x8 afA[8], afB[8];
    {
        const bf16x8* ap = (const bf16x8*)Apack;
        #pragma unroll
        for (int s = 0; s < 8; ++s) {
            afA[s] = ap[((size_t)itile * 8 + s) * 64 + lane];
            afB[s] = ap[((size_t)(itile + 1) * 8 + s) * 64 + lane];
        }
    }

    float rmaxA[16], rmaxB[16];
    #pragma unroll
    for (int r = 0; r < 16; ++r) { rmaxA[r] = -3.0e38f; rmaxB[r] = -3.0e38f; }

    // piece stream for this block's j-chunk (1024 pieces per half-panel)
    const bf16x8* gp = (const bf16x8*)Ppack + ((size_t)(jbase >> 5) * 8) * 64;
    bf16x8* sm = (bf16x8*)smem;

    bf16x8 tmp[4];
    #pragma unroll
    for (int h = 0; h < 4; ++h) tmp[h] = gp[tid + h * 256];
    #pragma unroll
    for (int h = 0; h < 4; ++h) sm[tid + h * 256] = tmp[h];
    __syncthreads();

    #pragma unroll 2
    for (int hp = 0; hp < NHP; ++hp) {
        if (hp + 1 < NHP) {
            #pragma unroll
            for (int h = 0; h < 4; ++h)
                tmp[h] = gp[(hp + 1) * 1024 + tid + h * 256];
        }

        const bf16x8* buf = sm + (hp & 1) * 1024;
        #pragma unroll
        for (int t = 0; t < 2; ++t) {
            const float ci = -0.5f * p_sq[jbase + (hp * 2 + t) * 32 + l31];
            f32x16 acc0, acc1;
            #pragma unroll
            for (int r = 0; r < 16; ++r) { acc0[r] = ci; acc1[r] = ci; }
            #pragma unroll
            for (int s = 0; s < 8; ++s) {
                bf16x8 b = buf[(t * 8 + s) * 64 + lane];
                acc0 = __builtin_amdgcn_mfma_f32_32x32x16_bf16(afA[s], b, acc0,
                                                               0, 0, 0);
                acc1 = __builtin_amdgcn_mfma_f32_32x32x16_bf16(afB[s], b, acc1,
                                                               0, 0, 0);
            }
            #pragma unroll
            for (int r = 0; r < 16; ++r) {
                rmaxA[r] = fmaxf(rmaxA[r], acc0[r]);
                rmaxB[r] = fmaxf(rmaxB[r], acc1[r]);
            }
        }

        if (hp + 1 < NHP) {
            bf16x8* w = sm + ((hp + 1) & 1) * 1024;
            #pragma unroll
            for (int h = 0; h < 4; ++h) w[tid + h * 256] = tmp[h];
            __syncthreads();
        }
    }

    // max across the 32 columns (lanes sharing the same half)
    #pragma unroll
    for (int r = 0; r < 16; ++r) {
        float vA = rmaxA[r], vB = rmaxB[r];
        #pragma unroll
        for (int off = 1; off <= 16; off <<= 1) {
            vA = fmaxf(vA, __shfl_xor(vA, off, 64));
            vB = fmaxf(vB, __shfl_xor(vB, off, 64));
        }
        rmaxA[r] = vA; rmaxB[r] = vB;
    }
    if (l31 == 0) {
        float* dst = partmax + (size_t)blockIdx.y * BS + i0;
        #pragma unroll
        for (int r = 0; r < 16; ++r) {
            int row = (r & 3) + 8 * (r >> 2) + 4 * half;
            dst[row]      = rmaxA[r];
            dst[row + 32] = rmaxB[r];
        }
    }
}

// ---------------------------------------------------------------------------
// fin stage 1: 32 blocks x 256 threads; thread handles exactly one i.
// min_j d2 = a_sq[i] - 2 * max_c partmax[c][i]
// ---------------------------------------------------------------------------
__global__ __launch_bounds__(256) void fin1_kernel(
        const float* __restrict__ partmax, const float* __restrict__ a_sq,
        const float* __restrict__ pd2, float* __restrict__ bsum)
{
    __shared__ float ssum[4];
    const int t = threadIdx.x;
    const int i = blockIdx.x * 256 + t;

    float m = -3.0e38f;
    #pragma unroll
    for (int c = 0; c < NJC; ++c)
        m = fmaxf(m, partmax[c * BS + i]);
    float negd = sqrtf(fmaxf(fmaf(-2.0f, m, a_sq[i]), 0.0f));
    float posd = sqrtf(pd2[i]);
    float sum = fmaxf(posd - negd + 1.0f, 0.0f);

    #pragma unroll
    for (int off = 32; off >= 1; off >>= 1) sum += __shfl_xor(sum, off, 64);
    if ((t & 63) == 0) ssum[t >> 6] = sum;
    __syncthreads();
    if (t == 0)
        bsum[blockIdx.x] = ssum[0] + ssum[1] + ssum[2] + ssum[3];
}

// fin stage 2: one wave sums the 32 block partials.
__global__ __launch_bounds__(64) void fin2_kernel(
        const float* __restrict__ bsum, float* __restrict__ out)
{
    const int t = threadIdx.x;
    float v = (t < 32) ? bsum[t] : 0.0f;
    #pragma unroll
    for (int off = 32; off >= 1; off >>= 1) v += __shfl_xor(v, off, 64);
    if (t == 0) out[0] = v / (float)BS;
}

// ---------------------------------------------------------------------------
extern "C" void kernel_launch(void* const* d_in, const int* in_sizes, int n_in,
                              void* d_out, int out_size, void* d_ws,
                              size_t ws_size, hipStream_t stream)
{
    const float* feats = (const float*)d_in[0];

    char* ws = (char*)d_ws;
    __bf16* Apack = (__bf16*)ws;  ws += (size_t)BS * D * 2;   // 2 MB
    __bf16* Ppack = (__bf16*)ws;  ws += (size_t)BS * D * 2;   // 2 MB
    float* a_sq   = (float*)ws;   ws += (size_t)BS * 4;
    float* p_sq   = (float*)ws;   ws += (size_t)BS * 4;
    float* pd2    = (float*)ws;   ws += (size_t)BS * 4;
    float* partmax = (float*)ws;  ws += (size_t)NJC * BS * 4; // 512 KB
    float* bsum   = (float*)ws;   ws += 32 * 4;

    pack_kernel<<<BS / 32, 256, 0, stream>>>(feats, Apack, Ppack,
                                             a_sq, p_sq, pd2);
    dim3 grid(BS / TI, NJC);
    max_kernel<<<grid, 256, 0, stream>>>(Apack, Ppack, p_sq, partmax);
    fin1_kernel<<<BS / 256, 256, 0, stream>>>(partmax, a_sq, pd2, bsum);
    fin2_kernel<<<1, 64, 0, stream>>>(bsum, (float*)d_out);
}

// Round 9
// 82.748 us; speedup vs baseline: 1.2836x; 1.0028x over previous
//
#include <hip/hip_runtime.h>

#define BS 8192
#define D  128
#define TI 128              // i-rows per block (2 waves x 64)
#define JCHUNK 512          // j's per block chunk
#define NJC (BS / JCHUNK)   // 16 (grid.y)
#define NHP 8               // panels per chunk (64 j-rows = 16 KB each)

#define AS1 __attribute__((address_space(1)))
#define AS3 __attribute__((address_space(3)))

typedef __bf16 bf16x8 __attribute__((ext_vector_type(8)));
typedef float  f32x16 __attribute__((ext_vector_type(16)));

// ---------------------------------------------------------------------------
// pack: feats -> fragment-major bf16 for BOTH anchor (Apack) and positive
// (Ppack), plus the fp32 row reductions (a_sq, p_sq, pd2). Layout (verified
// R6/R7/R8): piece ((tile*8 + s)*64 + lane) holds the 8 bf16 operand elements
// for MFMA lane `lane` at k-step s of 32-row tile `tile`:
//   row = tile*32 + (lane&31), k = s*16 + (lane>>5)*8 .. +8
// ---------------------------------------------------------------------------
__global__ __launch_bounds__(256) void pack_kernel(
        const float* __restrict__ feats,
        __bf16* __restrict__ Apack, __bf16* __restrict__ Ppack,
        float* __restrict__ a_sq, float* __restrict__ p_sq,
        float* __restrict__ pd2)
{
    const int tile = blockIdx.x;          // 0..255
    const int tid  = threadIdx.x;
    const int r    = tid >> 3;            // row within tile, 0..31
    const int kb   = tid & 7;             // k-block = MFMA step s, 0..7
    const int row  = tile * 32 + r;

    const float4* asrc = (const float4*)(feats + (size_t)row * D + kb * 16);
    const float4* psrc = (const float4*)(feats + (size_t)(row + BS) * D + kb * 16);
    float4 a0 = asrc[0], a1 = asrc[1], a2 = asrc[2], a3 = asrc[3];
    float4 p0 = psrc[0], p1 = psrc[1], p2 = psrc[2], p3 = psrc[3];

    bf16x8 alo, ahi, plo, phi;
    alo[0]=(__bf16)a0.x; alo[1]=(__bf16)a0.y; alo[2]=(__bf16)a0.z; alo[3]=(__bf16)a0.w;
    alo[4]=(__bf16)a1.x; alo[5]=(__bf16)a1.y; alo[6]=(__bf16)a1.z; alo[7]=(__bf16)a1.w;
    ahi[0]=(__bf16)a2.x; ahi[1]=(__bf16)a2.y; ahi[2]=(__bf16)a2.z; ahi[3]=(__bf16)a2.w;
    ahi[4]=(__bf16)a3.x; ahi[5]=(__bf16)a3.y; ahi[6]=(__bf16)a3.z; ahi[7]=(__bf16)a3.w;
    plo[0]=(__bf16)p0.x; plo[1]=(__bf16)p0.y; plo[2]=(__bf16)p0.z; plo[3]=(__bf16)p0.w;
    plo[4]=(__bf16)p1.x; plo[5]=(__bf16)p1.y; plo[6]=(__bf16)p1.z; plo[7]=(__bf16)p1.w;
    phi[0]=(__bf16)p2.x; phi[1]=(__bf16)p2.y; phi[2]=(__bf16)p2.z; phi[3]=(__bf16)p2.w;
    phi[4]=(__bf16)p3.x; phi[5]=(__bf16)p3.y; phi[6]=(__bf16)p3.z; phi[7]=(__bf16)p3.w;

    const size_t pb = ((size_t)tile * 8 + kb) * 64;
    ((bf16x8*)Apack)[pb + r]      = alo;
    ((bf16x8*)Apack)[pb + 32 + r] = ahi;
    ((bf16x8*)Ppack)[pb + r]      = plo;
    ((bf16x8*)Ppack)[pb + 32 + r] = phi;

    float sa = a0.x*a0.x + a0.y*a0.y + a0.z*a0.z + a0.w*a0.w
             + a1.x*a1.x + a1.y*a1.y + a1.z*a1.z + a1.w*a1.w
             + a2.x*a2.x + a2.y*a2.y + a2.z*a2.z + a2.w*a2.w
             + a3.x*a3.x + a3.y*a3.y + a3.z*a3.z + a3.w*a3.w;
    float sp = p0.x*p0.x + p0.y*p0.y + p0.z*p0.z + p0.w*p0.w
             + p1.x*p1.x + p1.y*p1.y + p1.z*p1.z + p1.w*p1.w
             + p2.x*p2.x + p2.y*p2.y + p2.z*p2.z + p2.w*p2.w
             + p3.x*p3.x + p3.y*p3.y + p3.z*p3.z + p3.w*p3.w;
    float d;
    float sd = 0.0f;
    d = a0.x-p0.x; sd += d*d;  d = a0.y-p0.y; sd += d*d;
    d = a0.z-p0.z; sd += d*d;  d = a0.w-p0.w; sd += d*d;
    d = a1.x-p1.x; sd += d*d;  d = a1.y-p1.y; sd += d*d;
    d = a1.z-p1.z; sd += d*d;  d = a1.w-p1.w; sd += d*d;
    d = a2.x-p2.x; sd += d*d;  d = a2.y-p2.y; sd += d*d;
    d = a2.z-p2.z; sd += d*d;  d = a2.w-p2.w; sd += d*d;
    d = a3.x-p3.x; sd += d*d;  d = a3.y-p3.y; sd += d*d;
    d = a3.z-p3.z; sd += d*d;  d = a3.w-p3.w; sd += d*d;

    #pragma unroll
    for (int off = 1; off <= 4; off <<= 1) {
        sa += __shfl_xor(sa, off, 64);
        sp += __shfl_xor(sp, off, 64);
        sd += __shfl_xor(sd, off, 64);
    }
    if (kb == 0) { a_sq[row] = sa; p_sq[row] = sp; pd2[row] = sd; }
}

// ---------------------------------------------------------------------------
// max kernel: block = 2 waves (128 thr), 128 i-rows x 512 j-chunk.
// 4 independent blocks/CU (launch_bounds(128,2): 8 waves/CU) so one block's
// stage/barrier phase hides behind three other blocks' compute.
// B streams as 8 panels of 64 j-rows (16 KB) through double-buffered LDS via
// global_load_lds (width 16) DMA — no VGPR round trip, no ds_writes: our
// fragment-major layout is exactly the DMA's wave-uniform-base + lane*16
// pattern. Prefetch of panel hp+1 issues right after the barrier, drains
// during hp's compute; __syncthreads' vmcnt(0) fences it.
//
// acc initialized to -p_sq[col]/2, so after K-loop acc = cross - p_sq/2 and
// min_j d2 = a_sq - 2 * max_j acc  -> epilogue = one v_max per reg.
//
// mfma_f32_32x32x16_bf16 C/D layout (HW-verified, learn_hip m74/m101):
//   col = lane&31, row = (reg&3) + 8*(reg>>2) + 4*(lane>>5)
// ---------------------------------------------------------------------------
__global__ __launch_bounds__(128, 2) void max_kernel(
        const __bf16* __restrict__ Apack, const __bf16* __restrict__ Ppack,
        const float* __restrict__ p_sq, float* __restrict__ partmax)
{
    __shared__ __bf16 smem[2 * 8192];           // 2 x 16 KB panel bufs

    const int tid  = threadIdx.x;               // 0..127
    const int wave = tid >> 6;                  // 0 or 1
    const int lane = tid & 63;
    const int l31  = lane & 31;
    const int half = lane >> 5;

    const int i0    = blockIdx.x * TI + wave * 64;    // wave's 64 anchor rows
    const int itile = i0 >> 5;
    const int jbase = blockIdx.y * JCHUNK;

    // A fragments, coalesced 1 KB wave-loads from fragment-major Apack
    bf16x8 afA[8], afB[8];
    {
        const bf16x8* ap = (const bf16x8*)Apack;
        #pragma unroll
        for (int s = 0; s < 8; ++s) {
            afA[s] = ap[((size_t)itile * 8 + s) * 64 + lane];
            afB[s] = ap[((size_t)(itile + 1) * 8 + s) * 64 + lane];
        }
    }

    float rmaxA[16], rmaxB[16];
    #pragma unroll
    for (int r = 0; r < 16; ++r) { rmaxA[r] = -3.0e38f; rmaxB[r] = -3.0e38f; }

    // piece stream for this block's j-chunk (1024 pieces = 16 KB per panel)
    const bf16x8* gp = (const bf16x8*)Ppack + ((size_t)(jbase >> 5) * 8) * 64;
    const bf16x8* sm = (const bf16x8*)smem;

    // DMA one panel: 1024 pieces, 8 per thread. Lane l of wave w, sub-step h
    // covers piece w*64 + l + h*128; LDS dest = wave-uniform base
    // ((bsel*1024 + w*64 + h*128)*16) + lane*16 — exact global_load_lds form.
    #define STAGE_PANEL(hp, bsel)                                            \
        {                                                                    \
            const bf16x8* gbase = gp + (size_t)(hp) * 1024 + wave * 64;      \
            char* lbase = (char*)smem +                                      \
                ((size_t)(bsel) * 1024 + wave * 64) * 16;                    \
            _Pragma("unroll")                                                \
            for (int h = 0; h < 8; ++h)                                      \
                __builtin_amdgcn_global_load_lds(                            \
                    (AS1 void*)(gbase + h * 128 + lane),                     \
                    (AS3 void*)(lbase + h * 128 * 16), 16, 0, 0);            \
        }

    STAGE_PANEL(0, 0)
    __syncthreads();

    #pragma unroll 2
    for (int hp = 0; hp < NHP; ++hp) {
        if (hp + 1 < NHP) STAGE_PANEL(hp + 1, (hp + 1) & 1)

        const bf16x8* buf = sm + (hp & 1) * 1024;
        #pragma unroll
        for (int t = 0; t < 2; ++t) {
            const float ci = -0.5f * p_sq[jbase + (hp * 2 + t) * 32 + l31];
            f32x16 acc0, acc1;
            #pragma unroll
            for (int r = 0; r < 16; ++r) { acc0[r] = ci; acc1[r] = ci; }
            #pragma unroll
            for (int s = 0; s < 8; ++s) {
                bf16x8 b = buf[(t * 8 + s) * 64 + lane];
                acc0 = __builtin_amdgcn_mfma_f32_32x32x16_bf16(afA[s], b, acc0,
                                                               0, 0, 0);
                acc1 = __builtin_amdgcn_mfma_f32_32x32x16_bf16(afB[s], b, acc1,
                                                               0, 0, 0);
            }
            #pragma unroll
            for (int r = 0; r < 16; ++r) {
                rmaxA[r] = fmaxf(rmaxA[r], acc0[r]);
                rmaxB[r] = fmaxf(rmaxB[r], acc1[r]);
            }
        }
        __syncthreads();
    }
    #undef STAGE_PANEL

    // max across the 32 columns (lanes sharing the same half)
    #pragma unroll
    for (int r = 0; r < 16; ++r) {
        float vA = rmaxA[r], vB = rmaxB[r];
        #pragma unroll
        for (int off = 1; off <= 16; off <<= 1) {
            vA = fmaxf(vA, __shfl_xor(vA, off, 64));
            vB = fmaxf(vB, __shfl_xor(vB, off, 64));
        }
        rmaxA[r] = vA; rmaxB[r] = vB;
    }
    if (l31 == 0) {
        float* dst = partmax + (size_t)blockIdx.y * BS + i0;
        #pragma unroll
        for (int r = 0; r < 16; ++r) {
            int row = (r & 3) + 8 * (r >> 2) + 4 * half;
            dst[row]      = rmaxA[r];
            dst[row + 32] = rmaxB[r];
        }
    }
}

// ---------------------------------------------------------------------------
// fin stage 1: 32 blocks x 256 threads; thread handles exactly one i.
// min_j d2 = a_sq[i] - 2 * max_c partmax[c][i]
// ---------------------------------------------------------------------------
__global__ __launch_bounds__(256) void fin1_kernel(
        const float* __restrict__ partmax, const float* __restrict__ a_sq,
        const float* __restrict__ pd2, float* __restrict__ bsum)
{
    __shared__ float ssum[4];
    const int t = threadIdx.x;
    const int i = blockIdx.x * 256 + t;

    float m = -3.0e38f;
    #pragma unroll
    for (int c = 0; c < NJC; ++c)
        m = fmaxf(m, partmax[c * BS + i]);
    float negd = sqrtf(fmaxf(fmaf(-2.0f, m, a_sq[i]), 0.0f));
    float posd = sqrtf(pd2[i]);
    float sum = fmaxf(posd - negd + 1.0f, 0.0f);

    #pragma unroll
    for (int off = 32; off >= 1; off >>= 1) sum += __shfl_xor(sum, off, 64);
    if ((t & 63) == 0) ssum[t >> 6] = sum;
    __syncthreads();
    if (t == 0)
        bsum[blockIdx.x] = ssum[0] + ssum[1] + ssum[2] + ssum[3];
}

// fin stage 2: one wave sums the 32 block partials.
__global__ __launch_bounds__(64) void fin2_kernel(
        const float* __restrict__ bsum, float* __restrict__ out)
{
    const int t = threadIdx.x;
    float v = (t < 32) ? bsum[t] : 0.0f;
    #pragma unroll
    for (int off = 32; off >= 1; off >>= 1) v += __shfl_xor(v, off, 64);
    if (t == 0) out[0] = v / (float)BS;
}

// ---------------------------------------------------------------------------
extern "C" void kernel_launch(void* const* d_in, const int* in_sizes, int n_in,
                              void* d_out, int out_size, void* d_ws,
                              size_t ws_size, hipStream_t stream)
{
    const float* feats = (const float*)d_in[0];

    char* ws = (char*)d_ws;
    __bf16* Apack = (__bf16*)ws;  ws += (size_t)BS * D * 2;   // 2 MB
    __bf16* Ppack = (__bf16*)ws;  ws += (size_t)BS * D * 2;   // 2 MB
    float* a_sq   = (float*)ws;   ws += (size_t)BS * 4;
    float* p_sq   = (float*)ws;   ws += (size_t)BS * 4;
    float* pd2    = (float*)ws;   ws += (size_t)BS * 4;
    float* partmax = (float*)ws;  ws += (size_t)NJC * BS * 4; // 512 KB
    float* bsum   = (float*)ws;   ws += 32 * 4;

    pack_kernel<<<BS / 32, 256, 0, stream>>>(feats, Apack, Ppack,
                                             a_sq, p_sq, pd2);
    dim3 grid(BS / TI, NJC);
    max_kernel<<<grid, 128, 0, stream>>>(Apack, Ppack, p_sq, partmax);
    fin1_kernel<<<BS / 256, 256, 0, stream>>>(partmax, a_sq, pd2, bsum);
    fin2_kernel<<<1, 64, 0, stream>>>(bsum, (float*)d_out);
}